// Round 1
// baseline (579.345 us; speedup 1.0000x reference)
//
#include <hip/hip_runtime.h>
#include <hip/hip_bf16.h>

// Problem constants (from reference): x [4,32,32,16,256] -> N=65536 rows, D=256
// embeddings [256, 4096] -> D=256, K=4096
#define NROWS 65536
#define DIM   256
#define KCB   4096

typedef __attribute__((ext_vector_type(8))) short bf16x8;  // 8 bf16 in 4 VGPRs
typedef __attribute__((ext_vector_type(4))) float f32x4;

__device__ inline short f2bf(float f) {
    __hip_bfloat16 h = __float2bfloat16(f);
    return *reinterpret_cast<short*>(&h);
}

// ---------------------------------------------------------------------------
// Prep 1: tiled transpose E[256][4096] -> ET32[4096][256] (f32) + ETbf (bf16)
// ---------------------------------------------------------------------------
__global__ void prep_transpose(const float* __restrict__ E,
                               float* __restrict__ ET32,
                               ushort* __restrict__ ETbf)
{
    __shared__ float tile[64][65];  // +1 pad: conflict-free both phases
    const int kb = blockIdx.x * 64;   // k block (4096/64 = 64)
    const int db = blockIdx.y * 64;   // d block (256/64 = 4)
    const int lo = threadIdx.x & 63;
    const int hi = threadIdx.x >> 6;  // 0..3

    // Phase 1: coalesced reads over k (lo = k-lane), 64 d-rows
#pragma unroll
    for (int i = 0; i < 16; ++i) {
        int d = i * 4 + hi;
        tile[lo][d] = E[(size_t)(db + d) * KCB + kb + lo];  // tile[k][d]
    }
    __syncthreads();
    // Phase 2: coalesced writes over d (lo = d-lane), 64 k-rows
#pragma unroll
    for (int i = 0; i < 16; ++i) {
        int k = i * 4 + hi;
        float v = tile[k][lo];
        size_t off = (size_t)(kb + k) * DIM + db + lo;
        ET32[off] = v;
        ETbf[off] = (ushort)f2bf(v);
    }
}

// ---------------------------------------------------------------------------
// Prep 2: column squared norms of E (fp32-exact)
// ---------------------------------------------------------------------------
__global__ void prep_enorm(const float* __restrict__ E, float* __restrict__ enorm2)
{
    int k = blockIdx.x * 256 + threadIdx.x;
    float s = 0.0f;
#pragma unroll 8
    for (int d = 0; d < DIM; ++d) {
        float v = E[(size_t)d * KCB + k];
        s = fmaf(v, v, s);
    }
    enorm2[k] = s;
}

// ---------------------------------------------------------------------------
// Fused GEMM + argmin. Block = 4 waves; wave owns 32 rows; loops 256 col-tiles.
// score = 2*(z.e_k) - ||e_k||^2, maximize  <=>  argmin dist
// ---------------------------------------------------------------------------
__global__ __launch_bounds__(256, 2)
void vq_argmin(const float* __restrict__ X,       // [65536][256]
               const ushort* __restrict__ ETbf,   // [4096][256] bf16
               const float* __restrict__ enorm2,  // [4096]
               int* __restrict__ idxout)          // [65536]
{
    const int tid  = threadIdx.x;
    const int lane = tid & 63;
    const int wave = tid >> 6;          // 0..3
    const int l15  = lane & 15;
    const int g    = lane >> 4;         // 0..3
    const long rowbase = (long)blockIdx.x * 128 + wave * 32;

    // A fragments: 2 row-tiles x 8 k-chunks, resident in VGPRs.
    // Lane holds A[row = l15][k = kc*32 + g*8 + j], j=0..7 (fp32 -> bf16 RNE).
    bf16x8 afrag[2][8];
#pragma unroll
    for (int rt = 0; rt < 2; ++rt) {
        const float* xr = X + (rowbase + rt * 16 + l15) * DIM;
#pragma unroll
        for (int kc = 0; kc < 8; ++kc) {
            int k0 = kc * 32 + g * 8;
            float4 v0 = *(const float4*)(xr + k0);
            float4 v1 = *(const float4*)(xr + k0 + 4);
            bf16x8 f;
            f[0] = f2bf(v0.x); f[1] = f2bf(v0.y);
            f[2] = f2bf(v0.z); f[3] = f2bf(v0.w);
            f[4] = f2bf(v1.x); f[5] = f2bf(v1.y);
            f[6] = f2bf(v1.z); f[7] = f2bf(v1.w);
            afrag[rt][kc] = f;
        }
    }

    float best[2][4];
    int   bidx[2][4];
#pragma unroll
    for (int rt = 0; rt < 2; ++rt)
#pragma unroll
        for (int r = 0; r < 4; ++r) { best[rt][r] = -3.4e38f; bidx[rt][r] = 0x7fffffff; }

    for (int ct = 0; ct < KCB / 16; ++ct) {
        const int col = ct * 16 + l15;
        // B fragments: lane holds B[k = kc*32 + g*8 + j][col = l15] = ETbf[col][k]
        const ushort* bcol = ETbf + (size_t)col * DIM + g * 8;
        bf16x8 bfrag[8];
#pragma unroll
        for (int kc = 0; kc < 8; ++kc)
            bfrag[kc] = *(const bf16x8*)(bcol + kc * 32);
        const float en = enorm2[col];

#pragma unroll
        for (int rt = 0; rt < 2; ++rt) {
            f32x4 acc = {0.f, 0.f, 0.f, 0.f};
#pragma unroll
            for (int kc = 0; kc < 8; ++kc)
                acc = __builtin_amdgcn_mfma_f32_16x16x32_bf16(afrag[rt][kc], bfrag[kc], acc, 0, 0, 0);
            // C/D: col = lane&15, row = (lane>>4)*4 + r  [HW-verified]
#pragma unroll
            for (int r = 0; r < 4; ++r) {
                float score = 2.0f * acc[r] - en;
                if (score > best[rt][r]) { best[rt][r] = score; bidx[rt][r] = col; }
            }
        }
    }

    // Reduce across the 16 lanes holding the same row (xor in low 4 bits).
#pragma unroll
    for (int rt = 0; rt < 2; ++rt) {
#pragma unroll
        for (int r = 0; r < 4; ++r) {
            float v = best[rt][r];
            int   ix = bidx[rt][r];
#pragma unroll
            for (int off = 1; off < 16; off <<= 1) {
                float ov = __shfl_xor(v, off, 64);
                int   oi = __shfl_xor(ix, off, 64);
                if (ov > v || (ov == v && oi < ix)) { v = ov; ix = oi; }
            }
            if (l15 == 0) {
                long row = rowbase + rt * 16 + g * 4 + r;
                idxout[row] = ix;
            }
        }
    }
}

// ---------------------------------------------------------------------------
// Gather nearest codebook rows (coalesced from ET32) + histogram
// ---------------------------------------------------------------------------
__global__ void vq_gather(const int* __restrict__ idxin,
                          const float* __restrict__ ET32,
                          float* __restrict__ out,
                          unsigned* __restrict__ counts)
{
    const int tid = threadIdx.x;
    const long n  = (long)blockIdx.x * 4 + (tid >> 6);
    const int d4  = tid & 63;
    const int idx = idxin[n];  // wave-uniform broadcast
    float4 v = *(const float4*)(ET32 + (size_t)idx * DIM + d4 * 4);
    *(float4*)(out + n * DIM + d4 * 4) = v;
    if (d4 == 0) atomicAdd(&counts[idx], 1u);
}

// ---------------------------------------------------------------------------
// Perplexity = exp(-sum p*log(p+1e-10)), p = counts/N
// ---------------------------------------------------------------------------
__global__ void vq_perplexity(const unsigned* __restrict__ counts, float* __restrict__ outp)
{
    __shared__ float wsum[4];
    const int tid = threadIdx.x;
    float s = 0.0f;
    for (int k = tid; k < KCB; k += 256) {
        float p = (float)counts[k] * (1.0f / (float)NROWS);
        s += p * logf(p + 1e-10f);
    }
#pragma unroll
    for (int off = 32; off >= 1; off >>= 1) s += __shfl_down(s, off, 64);
    if ((tid & 63) == 0) wsum[tid >> 6] = s;
    __syncthreads();
    if (tid == 0) outp[0] = expf(-(wsum[0] + wsum[1] + wsum[2] + wsum[3]));
}

// ---------------------------------------------------------------------------
extern "C" void kernel_launch(void* const* d_in, const int* in_sizes, int n_in,
                              void* d_out, int out_size, void* d_ws, size_t ws_size,
                              hipStream_t stream)
{
    const float* X = (const float*)d_in[0];   // x, 65536*256
    const float* E = (const float*)d_in[1];   // embeddings, 256*4096
    float* out = (float*)d_out;               // [65536*256 quantized][1 perplexity]

    char* ws = (char*)d_ws;
    float*    ET32   = (float*)ws;                                   // 4 MB
    ushort*   ETbf   = (ushort*)(ws + (size_t)KCB * DIM * 4);        // 2 MB
    float*    enrm   = (float*)(ws + (size_t)KCB * DIM * 6);         // 16 KB
    int*      idxbuf = (int*)(ws + (size_t)KCB * DIM * 6 + KCB * 4); // 256 KB
    unsigned* counts = (unsigned*)(ws + (size_t)KCB * DIM * 6 + KCB * 4 + NROWS * 4); // 16 KB

    hipMemsetAsync(counts, 0, KCB * sizeof(unsigned), stream);

    dim3 b256(256);
    prep_transpose<<<dim3(KCB / 64, DIM / 64), b256, 0, stream>>>(E, ET32, ETbf);
    prep_enorm<<<KCB / 256, b256, 0, stream>>>(E, enrm);
    vq_argmin<<<NROWS / 128, b256, 0, stream>>>(X, ETbf, enrm, idxbuf);
    vq_gather<<<NROWS / 4, b256, 0, stream>>>(idxbuf, ET32, out, counts);
    vq_perplexity<<<1, b256, 0, stream>>>(counts, out + (size_t)NROWS * DIM);
}

// Round 3
// 193.904 us; speedup vs baseline: 2.9878x; 2.9878x over previous
//
#include <hip/hip_runtime.h>
#include <hip/hip_bf16.h>

// Problem constants: x [4,32,32,16,256] -> N=65536 rows, D=256
// embeddings [256, 4096] -> D=256, K=4096
#define NROWS 65536
#define DIM   256
#define KCB   4096

typedef __attribute__((ext_vector_type(8))) short bf16x8;  // 8 bf16 in 4 VGPRs
typedef __attribute__((ext_vector_type(4))) float f32x4;

__device__ inline short f2bf(float f) {
    __hip_bfloat16 h = __float2bfloat16(f);
    return *reinterpret_cast<short*>(&h);
}

// ---------------------------------------------------------------------------
// Prep 1: tiled transpose E[256][4096] -> ET32[4096][256] (f32) + ETbf (bf16)
// ---------------------------------------------------------------------------
__global__ void prep_transpose(const float* __restrict__ E,
                               float* __restrict__ ET32,
                               ushort* __restrict__ ETbf)
{
    __shared__ float tile[64][65];
    const int kb = blockIdx.x * 64;
    const int db = blockIdx.y * 64;
    const int lo = threadIdx.x & 63;
    const int hi = threadIdx.x >> 6;

#pragma unroll
    for (int i = 0; i < 16; ++i) {
        int d = i * 4 + hi;
        tile[lo][d] = E[(size_t)(db + d) * KCB + kb + lo];
    }
    __syncthreads();
#pragma unroll
    for (int i = 0; i < 16; ++i) {
        int k = i * 4 + hi;
        float v = tile[k][lo];
        size_t off = (size_t)(kb + k) * DIM + db + lo;
        ET32[off] = v;
        ETbf[off] = (ushort)f2bf(v);
    }
}

// ---------------------------------------------------------------------------
// Prep 2: column squared norms of E (fp32-exact)
// ---------------------------------------------------------------------------
__global__ void prep_enorm(const float* __restrict__ E, float* __restrict__ enorm2)
{
    int k = blockIdx.x * 256 + threadIdx.x;
    float s = 0.0f;
#pragma unroll 8
    for (int d = 0; d < DIM; ++d) {
        float v = E[(size_t)d * KCB + k];
        s = fmaf(v, v, s);
    }
    enorm2[k] = s;
}

// ---------------------------------------------------------------------------
// Fused GEMM + argmin, LDS-staged B (m97-style 2-phase double buffer).
// Block = 4 waves x 32 rows = 128 rows. Loop: 64 chunks of 64 cols.
// Per chunk: stage 64 cols x 512B = 32KB via global_load_lds (16B issues,
// 8 issues/wave = 8KB slice/wave). Source address carries the XOR swizzle
// (slot ^= col&7) so the ds_read side can use the same XOR (both-sides rule).
// score = 2*(z.e_k) - ||e_k||^2, maximize <=> argmin dist.
// ---------------------------------------------------------------------------
__global__ __launch_bounds__(256, 2)
void vq_argmin(const float* __restrict__ X,       // [65536][256] f32
               const ushort* __restrict__ ETbf,   // [4096][256] bf16
               const float* __restrict__ enorm2,  // [4096]
               int* __restrict__ idxout)          // [65536]
{
    __shared__ ushort smem[2][64 * DIM];          // 2 x 32KB double buffer
    const int tid  = threadIdx.x;
    const int lane = tid & 63;
    const int wave = tid >> 6;          // 0..3
    const int l15  = lane & 15;
    const int g    = lane >> 4;         // 0..3
    const long rowbase = (long)blockIdx.x * 128 + wave * 32;

    // A fragments resident in VGPRs: lane holds A[row=l15][k=kc*32+g*8+j].
    bf16x8 afrag[2][8];
#pragma unroll
    for (int rt = 0; rt < 2; ++rt) {
        const float* xr = X + (rowbase + rt * 16 + l15) * DIM;
#pragma unroll
        for (int kc = 0; kc < 8; ++kc) {
            int k0 = kc * 32 + g * 8;
            float4 v0 = *(const float4*)(xr + k0);
            float4 v1 = *(const float4*)(xr + k0 + 4);
            bf16x8 f;
            f[0] = f2bf(v0.x); f[1] = f2bf(v0.y);
            f[2] = f2bf(v0.z); f[3] = f2bf(v0.w);
            f[4] = f2bf(v1.x); f[5] = f2bf(v1.y);
            f[6] = f2bf(v1.z); f[7] = f2bf(v1.w);
            afrag[rt][kc] = f;
        }
    }

    float best[2][4];
    int   bidx[2][4];
#pragma unroll
    for (int rt = 0; rt < 2; ++rt)
#pragma unroll
        for (int r = 0; r < 4; ++r) { best[rt][r] = -3.4e38f; bidx[rt][r] = 0x7fffffff; }

    // Stage chunk ct (64 cols, 32KB) into smem[buf]. Each wave fills its 8KB
    // slice with 8 issues of 64 lanes x 16B = 1KB each. LDS dest is linear
    // (wave-uniform base + lane*16); XOR swizzle applied on the GLOBAL source.
    auto stage = [&](int buf, int ct) {
#pragma unroll
        for (int j = 0; j < 8; ++j) {
            const int o   = wave * 8192 + j * 1024 + lane * 16;  // lds byte off
            const int col = o >> 9;            // 0..63 within chunk
            const int cph = (o >> 4) & 31;     // physical 16B slot in row
            const char* src = (const char*)ETbf
                + ((size_t)(ct * 64 + col) << 9)       // row base (512B rows)
                + ((size_t)(cph ^ (col & 7)) << 4);    // swizzled 16B slot
            __builtin_amdgcn_global_load_lds(
                (const __attribute__((address_space(1))) unsigned*)src,
                (__attribute__((address_space(3))) unsigned*)
                    ((char*)&smem[buf][0] + wave * 8192 + j * 1024),
                16, 0, 0);
        }
    };

    stage(0, 0);
    int cur = 0;
    for (int ct = 0; ct < KCB / 64; ++ct) {
        __syncthreads();                 // drains vmcnt: smem[cur] staged
        if (ct < KCB / 64 - 1) stage(cur ^ 1, ct + 1);  // overlap next stage

        const char* bb = (const char*)&smem[cur][0];
#pragma unroll
        for (int tc = 0; tc < 4; ++tc) {
            const int cl = tc * 16 + l15;           // col within chunk
            bf16x8 bfrag[8];
#pragma unroll
            for (int kc = 0; kc < 8; ++kc) {
                // logical 16B slot = kc*4+g  (ushort off kc*32+g*8)
                int off = (cl << 9) + ((((kc << 2) + g) ^ (cl & 7)) << 4);
                bfrag[kc] = *(const bf16x8*)(bb + off);
            }
            const int col = ct * 64 + cl;
            const float en = enorm2[col];
            f32x4 acc0 = {0.f, 0.f, 0.f, 0.f};
            f32x4 acc1 = {0.f, 0.f, 0.f, 0.f};
#pragma unroll
            for (int kc = 0; kc < 8; ++kc) {
                acc0 = __builtin_amdgcn_mfma_f32_16x16x32_bf16(afrag[0][kc], bfrag[kc], acc0, 0, 0, 0);
                acc1 = __builtin_amdgcn_mfma_f32_16x16x32_bf16(afrag[1][kc], bfrag[kc], acc1, 0, 0, 0);
            }
            // C/D: col = lane&15, row = (lane>>4)*4 + r  [HW-verified]
#pragma unroll
            for (int r = 0; r < 4; ++r) {
                float s0 = 2.0f * acc0[r] - en;
                if (s0 > best[0][r]) { best[0][r] = s0; bidx[0][r] = col; }
                float s1 = 2.0f * acc1[r] - en;
                if (s1 > best[1][r]) { best[1][r] = s1; bidx[1][r] = col; }
            }
        }
        cur ^= 1;
    }

    // Reduce across the 16 lanes holding the same row (xor in low 4 bits).
#pragma unroll
    for (int rt = 0; rt < 2; ++rt) {
#pragma unroll
        for (int r = 0; r < 4; ++r) {
            float v = best[rt][r];
            int   ix = bidx[rt][r];
#pragma unroll
            for (int off = 1; off < 16; off <<= 1) {
                float ov = __shfl_xor(v, off, 64);
                int   oi = __shfl_xor(ix, off, 64);
                if (ov > v || (ov == v && oi < ix)) { v = ov; ix = oi; }
            }
            if (l15 == 0) {
                long row = rowbase + rt * 16 + g * 4 + r;
                idxout[row] = ix;
            }
        }
    }
}

// ---------------------------------------------------------------------------
// Gather nearest codebook rows (coalesced from ET32) + histogram
// ---------------------------------------------------------------------------
__global__ void vq_gather(const int* __restrict__ idxin,
                          const float* __restrict__ ET32,
                          float* __restrict__ out,
                          unsigned* __restrict__ counts)
{
    const int tid = threadIdx.x;
    const long n  = (long)blockIdx.x * 4 + (tid >> 6);
    const int d4  = tid & 63;
    const int idx = idxin[n];
    float4 v = *(const float4*)(ET32 + (size_t)idx * DIM + d4 * 4);
    *(float4*)(out + n * DIM + d4 * 4) = v;
    if (d4 == 0) atomicAdd(&counts[idx], 1u);
}

// ---------------------------------------------------------------------------
// Perplexity = exp(-sum p*log(p+1e-10)), p = counts/N
// ---------------------------------------------------------------------------
__global__ void vq_perplexity(const unsigned* __restrict__ counts, float* __restrict__ outp)
{
    __shared__ float wsum[4];
    const int tid = threadIdx.x;
    float s = 0.0f;
    for (int k = tid; k < KCB; k += 256) {
        float p = (float)counts[k] * (1.0f / (float)NROWS);
        s += p * logf(p + 1e-10f);
    }
#pragma unroll
    for (int off = 32; off >= 1; off >>= 1) s += __shfl_down(s, off, 64);
    if ((tid & 63) == 0) wsum[tid >> 6] = s;
    __syncthreads();
    if (tid == 0) outp[0] = expf(-(wsum[0] + wsum[1] + wsum[2] + wsum[3]));
}

// ---------------------------------------------------------------------------
extern "C" void kernel_launch(void* const* d_in, const int* in_sizes, int n_in,
                              void* d_out, int out_size, void* d_ws, size_t ws_size,
                              hipStream_t stream)
{
    const float* X = (const float*)d_in[0];
    const float* E = (const float*)d_in[1];
    float* out = (float*)d_out;

    char* ws = (char*)d_ws;
    float*    ET32   = (float*)ws;                                   // 4 MB
    ushort*   ETbf   = (ushort*)(ws + (size_t)KCB * DIM * 4);        // 2 MB
    float*    enrm   = (float*)(ws + (size_t)KCB * DIM * 6);         // 16 KB
    int*      idxbuf = (int*)(ws + (size_t)KCB * DIM * 6 + KCB * 4); // 256 KB
    unsigned* counts = (unsigned*)(ws + (size_t)KCB * DIM * 6 + KCB * 4 + NROWS * 4); // 16 KB

    hipMemsetAsync(counts, 0, KCB * sizeof(unsigned), stream);

    dim3 b256(256);
    prep_transpose<<<dim3(KCB / 64, DIM / 64), b256, 0, stream>>>(E, ET32, ETbf);
    prep_enorm<<<KCB / 256, b256, 0, stream>>>(E, enrm);
    vq_argmin<<<NROWS / 128, b256, 0, stream>>>(X, ETbf, enrm, idxbuf);
    vq_gather<<<NROWS / 4, b256, 0, stream>>>(idxbuf, ET32, out, counts);
    vq_perplexity<<<1, b256, 0, stream>>>(counts, out + (size_t)NROWS * DIM);
}